// Round 8
// baseline (229.112 us; speedup 1.0000x reference)
//
#include <hip/hip_runtime.h>

typedef _Float16 f16;
typedef _Float16 f16x8 __attribute__((ext_vector_type(8)));
typedef _Float16 f16x4 __attribute__((ext_vector_type(4)));
typedef __fp16 h16x2 __attribute__((ext_vector_type(2)));
typedef float f32x4 __attribute__((ext_vector_type(4)));

#define MFMA32(a, b, c) __builtin_amdgcn_mfma_f32_16x16x32_f16((a), (b), (c), 0, 0, 0)

static constexpr int Bb = 2, T = 2048, H = 1024, NH = 16, HD = 64;
static constexpr int M = Bb * T;      // 4096 rows
static constexpr int NQK = 2 * H;     // QK buffer row stride (Q | K)
// fold 1/sqrt(64) * log2(e) into Wq/bq so P = 2^S via raw v_exp_f32
#define QSCALE 0.1803368801111f

__device__ __forceinline__ void gload_lds16(const void* g, void* l) {
  __builtin_amdgcn_global_load_lds(
      (const __attribute__((address_space(1))) void*)g,
      (__attribute__((address_space(3))) void*)l, 16, 0, 0);
}

// ---------- fused pack kernel ----------
__global__ __launch_bounds__(256) void pack_all(const float* __restrict__ x,
                                                const float* __restrict__ Wq,
                                                const float* __restrict__ Wk,
                                                const float* __restrict__ Wv,
                                                const float* __restrict__ Wo,
                                                const float* __restrict__ bq,
                                                const float* __restrict__ bk,
                                                const float* __restrict__ bv,
                                                const int* __restrict__ mask,
                                                f16* __restrict__ xh,
                                                f16* __restrict__ WqkvT,
                                                f16* __restrict__ WoT,
                                                float* __restrict__ bqkv,
                                                float* __restrict__ maskf) {
  __shared__ f16 tile[64][65];
  const int bid = blockIdx.x;
  if (bid < 4096) {
    int i = bid * 256 + threadIdx.x;
    float4 v = ((const float4*)x)[i];
    f16x4 o;
    o[0] = (f16)v.x; o[1] = (f16)v.y; o[2] = (f16)v.z; o[3] = (f16)v.w;
    *(f16x4*)(xh + (size_t)i * 4) = o;
  } else if (bid < 5120) {
    int t = bid - 4096;
    int z = t >> 8, rem = t & 255;
    const float* W = (z == 0) ? Wq : (z == 1) ? Wk : (z == 2) ? Wv : Wo;
    f16* Wt = (z < 3) ? (WqkvT + (size_t)z * H * H) : WoT;
    const float scale = (z == 0) ? QSCALE : 1.0f;
    int k0 = (rem >> 4) * 64, n0 = (rem & 15) * 64;
    for (int p = 0; p < 16; ++p) {
      int idx = threadIdx.x + p * 256;
      int r = idx >> 6, c = idx & 63;
      tile[r][c] = (f16)(W[(size_t)(k0 + r) * H + n0 + c] * scale);
    }
    __syncthreads();
    for (int p = 0; p < 16; ++p) {
      int idx = threadIdx.x + p * 256;
      int r = idx >> 6, c = idx & 63;
      Wt[(size_t)(n0 + r) * H + k0 + c] = tile[c][r];
    }
  } else if (bid < 5132) {
    int i = (bid - 5120) * 256 + threadIdx.x;
    if (i < 3072) {
      float v = (i < 1024) ? bq[i] * QSCALE : ((i < 2048) ? bk[i - 1024] : bv[i - 2048]);
      bqkv[i] = v;
    }
  } else {
    int i = (bid - 5132) * 256 + threadIdx.x;
    // log2-domain mask bias: P = exp2(S + bias); 0 keeps, -3e4 kills (exp2 -> 0)
    if (i < Bb * T) maskf[i] = mask[i] ? 0.0f : -30000.0f;
  }
}

// LDS rows of 64 f16 = 8 granules; slot s of row r holds granule s^(r&7).
__device__ __forceinline__ f16x8 lds_frag(const f16* base, int row, int gr) {
  return *(const f16x8*)(base + row * 64 + ((gr ^ (row & 7)) << 3));
}

// ---------- GEMM1: [xh @ WqkvT^T + b] -> QK (n<2048) / VT transposed (n>=2048)
// r2-proven shape: TM=128, TN=64, (256,3) -> 3 blocks/CU. 8-phase 256^2
// rebuild regressed at K=1024 (r7: 52us, MfmaUtil 17.9 -- doesn't amortize
// at 16 K-tiles / 1 block/CU). No XCD swizzle (r2 config = best total).
__global__ __launch_bounds__(256, 3) void gemm_qkv(const f16* __restrict__ A,
                                                   const f16* __restrict__ Bt,
                                                   const float* __restrict__ bias,
                                                   f16* __restrict__ QK,
                                                   f16* __restrict__ VT) {
  constexpr int TM = 128, TN = 64, Kk = 1024;
  __shared__ f16 As[2][TM * 64];
  __shared__ f16 Bs[2][TN * 64];
  const int tid = threadIdx.x;
  const int lane = tid & 63, w = tid >> 6;
  const int quad = lane >> 4, l16 = lane & 15;
  const int wm = w >> 1, wn = w & 1;
  const int m0 = blockIdx.y * TM, n0 = blockIdx.x * TN;

  f32x4 acc[4][2];
  for (int a = 0; a < 4; ++a)
    for (int b2 = 0; b2 < 2; ++b2)
      for (int r = 0; r < 4; ++r) acc[a][b2][r] = 0.f;

  auto stage = [&](int k0, int buf) {
    for (int p = 0; p < 4; ++p) {
      int slot = p * 256 + w * 64 + lane;
      int r = slot >> 3, g = (slot & 7) ^ (r & 7);
      gload_lds16(A + (size_t)(m0 + r) * Kk + k0 + g * 8,
                  (char*)&As[buf][0] + (p * 256 + w * 64) * 16);
    }
    for (int p = 0; p < 2; ++p) {
      int slot = p * 256 + w * 64 + lane;
      int r = slot >> 3, g = (slot & 7) ^ (r & 7);
      gload_lds16(Bt + (size_t)(n0 + r) * Kk + k0 + g * 8,
                  (char*)&Bs[buf][0] + (p * 256 + w * 64) * 16);
    }
  };

  stage(0, 0);
  __syncthreads();
  for (int it = 0; it < Kk / 64; ++it) {
    const int cur = it & 1;
    if (it + 1 < Kk / 64) stage((it + 1) * 64, cur ^ 1);
    for (int ks = 0; ks < 2; ++ks) {
      f16x8 af[4], bf[2];
      for (int t = 0; t < 4; ++t)
        af[t] = lds_frag(&As[cur][0], wm * 64 + t * 16 + l16, ks * 4 + quad);
      for (int t = 0; t < 2; ++t)
        bf[t] = lds_frag(&Bs[cur][0], wn * 32 + t * 16 + l16, ks * 4 + quad);
      for (int tm = 0; tm < 4; ++tm)
        for (int tn = 0; tn < 2; ++tn)
          acc[tm][tn] = MFMA32(af[tm], bf[tn], acc[tm][tn]);
    }
    __syncthreads();
  }

  if (n0 < 2048) {
    for (int tm = 0; tm < 4; ++tm)
      for (int tn = 0; tn < 2; ++tn) {
        int n = n0 + wn * 32 + tn * 16 + l16;
        float bn = bias[n];
        for (int r = 0; r < 4; ++r) {
          int m = m0 + wm * 64 + tm * 16 + quad * 4 + r;
          QK[(size_t)m * NQK + n] = (f16)(acc[tm][tn][r] + bn);
        }
      }
  } else {
    for (int tm = 0; tm < 4; ++tm)
      for (int tn = 0; tn < 2; ++tn) {
        int ng = n0 + wn * 32 + tn * 16 + l16;
        float bn = bias[ng];
        int n = ng - 2048;
        int h = n >> 6, d = n & 63;
        int mrow = m0 + wm * 64 + tm * 16 + quad * 4;
        int bb = mrow >> 11, t = mrow & 2047;
        int c = (t & ~127) | ((t + 8 * (d & 15)) & 127);
        f16x4 o;
        for (int r = 0; r < 4; ++r) o[r] = (f16)(acc[tm][tn][r] + bn);
        *(f16x4*)(VT + ((size_t)(bb * NH + h) * HD + d) * T + c) = o;
      }
  }
}

// ---------- merged attention + output GEMM (one launch, manual grid barrier) --
// Part 1 = v11 attn (r2/r5-proven). Part 2 = out = ctx @ WoT^T + bo, 128x128
// tile per block (256 tiles = 256 blocks exactly), 8 waves (2x4), smem reuse.
// Grid barrier: 256 blocks <= structural co-residency (70656B LDS, ~112 VGPR
// -> 2 blocks/CU capacity; grid = 1/CU), device-scope atomic arrive counter
// (zeroed by hipMemsetAsync per launch) + __threadfence release/acquire for
// cross-XCD ctx visibility (G16: device-scope atomics/fences suffice).

static constexpr int KT_ELE = 128 * 64;
static constexpr int VT_ELE = 64 * 128;

__global__ __launch_bounds__(512, 2) void attn_out(const f16* __restrict__ QK,
                                                   const f16* __restrict__ VT,
                                                   const float* __restrict__ maskf,
                                                   f16* __restrict__ ctx,
                                                   const f16* __restrict__ WoT,
                                                   const float* __restrict__ bo,
                                                   float* __restrict__ out,
                                                   unsigned* __restrict__ gctr) {
  __shared__ __align__(16) char smem[70656];  // attn staging 64KB | combine 70.6KB | gemm 64KB
  f16* KtB = (f16*)smem;
  f16* VtB = (f16*)(smem + 2 * KT_ELE * 2);

  const int tid = threadIdx.x;
  const int w = tid >> 6, lane = tid & 63;
  const int quad = lane >> 4, l16 = lane & 15;
  const int qw = w & 3, g = w >> 2;

  // ===================== part 1: flash attention (v11) =====================
  {
    // XCD-aware bijective swizzle (256 blocks % 8 XCDs == 0):
    // each XCD gets 4 (b,h) pairs x 8 q-blocks -> K/V working set 2MB < 4MB L2
    const int flat = blockIdx.x;
    const int xcd = flat & 7, idx = flat >> 3;   // idx 0..31 per XCD
    const int bh = xcd * 4 + (idx >> 3);         // 4 (b,h) pairs per XCD
    const int qb = idx & 7;                      // 8 q-blocks per (b,h)
    const int h = bh & 15, b = bh >> 4;
    const int q0 = qb * 256;

    const size_t kbase = (size_t)(b * T) * NQK + H + h * HD;
    const size_t vtbase = ((size_t)(b * NH + h) * HD) * T;
    const float* maskp = maskf + b * T;

    // Q B-frags
    f16x8 qf[4][2];
    for (int tq = 0; tq < 4; ++tq) {
      const f16* qrow = QK + (size_t)(b * T + q0 + qw * 64 + tq * 16 + l16) * NQK + h * HD;
      qf[tq][0] = *(const f16x8*)(qrow + quad * 8);
      qf[tq][1] = *(const f16x8*)(qrow + 32 + quad * 8);
    }

    f16x8 onesf;
    for (int i = 0; i < 8; ++i) onesf[i] = (f16)1.0f;

    f32x4 oacc[4][4];
    f32x4 lacc[4];
    for (int tq = 0; tq < 4; ++tq) {
      for (int r = 0; r < 4; ++r) lacc[tq][r] = 0.f;
      for (int t = 0; t < 4; ++t)
        for (int r = 0; r < 4; ++r) oacc[tq][t][r] = 0.f;
    }

    auto stage = [&](int kv0, int buf) {
      f16* Kd = KtB + buf * KT_ELE;
      f16* Vd = VtB + buf * VT_ELE;
      for (int p = 0; p < 2; ++p) {
        int s = p * 512 + tid;
        int R = s >> 3, sg = (s & 7) ^ (R & 7);
        int kv = (R & ~31) | ((R & 12) << 1) | ((R & 16) >> 2) | (R & 3);
        gload_lds16(QK + kbase + (size_t)(kv0 + kv) * NQK + sg * 8,
                    (char*)Kd + (p * 512 + w * 64) * 16);
      }
      for (int p = 0; p < 2; ++p) {
        int s = p * 512 + tid;
        int d = s >> 4, cg = s & 15;
        gload_lds16(VT + vtbase + (size_t)d * T + kv0 + cg * 8,
                    (char*)Vd + (p * 512 + w * 64) * 16);
      }
    };

    stage(0, 0);
    __syncthreads();

    for (int it = 0; it < T / 128; ++it) {
      const int cur = it & 1;
      if (it + 1 < T / 128) stage((it + 1) * 128, cur ^ 1);

      const f16* Kc = KtB + cur * KT_ELE;
      const f16* Vc = VtB + cur * VT_ELE;

      for (int s = 0; s < 2; ++s) {
        const int bi = g * 2 + s;               // 32-kv block index in tile
        const int kvabs = it * 128 + bi * 32;
        float4 m0 = *(const float4*)(maskp + kvabs + quad * 8);
        float4 m1 = *(const float4*)(maskp + kvabs + quad * 8 + 4);
        f32x4 zA, zB;
        zA[0] = m0.x; zA[1] = m0.y; zA[2] = m0.z; zA[3] = m0.w;
        zB[0] = m1.x; zB[1] = m1.y; zB[2] = m1.z; zB[3] = m1.w;
        f16x8 kfA0 = lds_frag(Kc, bi * 32 + l16, quad);
        f16x8 kfA1 = lds_frag(Kc, bi * 32 + l16, 4 + quad);
        f16x8 kfB0 = lds_frag(Kc, bi * 32 + 16 + l16, quad);
        f16x8 kfB1 = lds_frag(Kc, bi * 32 + 16 + l16, 4 + quad);
        f16x8 vf[4];
        for (int td = 0; td < 4; ++td)
          vf[td] = *(const f16x8*)&Vc[(td * 16 + l16) * 128 +
                                      ((bi * 32 + quad * 8 + 8 * l16) & 127)];

        // phase 1: all QK MFMAs (16, independent chains of 2); mask bias as C-in
        f32x4 sA[4], sB[4];
        for (int tq = 0; tq < 4; ++tq) {
          sA[tq] = MFMA32(kfA0, qf[tq][0], zA);
          sB[tq] = MFMA32(kfB0, qf[tq][0], zB);
        }
        for (int tq = 0; tq < 4; ++tq) {
          sA[tq] = MFMA32(kfA1, qf[tq][1], sA[tq]);
          sB[tq] = MFMA32(kfB1, qf[tq][1], sB[tq]);
        }

        // phase 2: softmax VALU (exp2 + pack only)
        f16x8 pf[4];
        for (int tq = 0; tq < 4; ++tq) {
          float pA0 = __builtin_amdgcn_exp2f(sA[tq][0]);
          float pA1 = __builtin_amdgcn_exp2f(sA[tq][1]);
          float pA2 = __builtin_amdgcn_exp2f(sA[tq][2]);
          float pA3 = __builtin_amdgcn_exp2f(sA[tq][3]);
          float pB0 = __builtin_amdgcn_exp2f(sB[tq][0]);
          float pB1 = __builtin_amdgcn_exp2f(sB[tq][1]);
          float pB2 = __builtin_amdgcn_exp2f(sB[tq][2]);
          float pB3 = __builtin_amdgcn_exp2f(sB[tq][3]);
          union PF { f16x8 v; h16x2 h[4]; } u;
          u.h[0] = __builtin_amdgcn_cvt_pkrtz(pA0, pA1);
          u.h[1] = __builtin_amdgcn_cvt_pkrtz(pA2, pA3);
          u.h[2] = __builtin_amdgcn_cvt_pkrtz(pB0, pB1);
          u.h[3] = __builtin_amdgcn_cvt_pkrtz(pB2, pB3);
          pf[tq] = u.v;
        }

        // phase 3: all PV MFMAs + ones-MFMA row-sum (20, independent accumulators)
        for (int tq = 0; tq < 4; ++tq) {
          for (int td = 0; td < 4; ++td)
            oacc[tq][td] = MFMA32(vf[td], pf[tq], oacc[tq][td]);
          lacc[tq] = MFMA32(onesf, pf[tq], lacc[tq]);
        }
      }
      __syncthreads();
    }

    // ---- combine the 2 kv-groups (additive partials; 68 floats, stride 69) --
    float* cmb = (float*)smem;
    const int slot = qw * 64 + lane;
    if (g == 1) {
      float* dst = cmb + slot * 69;
      int i = 0;
      for (int tq = 0; tq < 4; ++tq)
        for (int td = 0; td < 4; ++td)
          for (int r = 0; r < 4; ++r) dst[i++] = oacc[tq][td][r];
      for (int tq = 0; tq < 4; ++tq) dst[64 + tq] = lacc[tq][0];
    }
    __syncthreads();
    if (g == 0) {
      const float* src = cmb + slot * 69;
      int i = 0;
      for (int tq = 0; tq < 4; ++tq)
        for (int td = 0; td < 4; ++td)
          for (int r = 0; r < 4; ++r) oacc[tq][td][r] += src[i++];

      for (int tq = 0; tq < 4; ++tq) {
        float l = lacc[tq][0] + src[64 + tq];
        float inv = 1.f / l;
        int row = b * T + q0 + qw * 64 + tq * 16 + l16;
        for (int td = 0; td < 4; ++td) {
          f16x4 o;
          for (int r = 0; r < 4; ++r) o[r] = (f16)(oacc[tq][td][r] * inv);
          *(f16x4*)(ctx + (size_t)row * H + h * HD + td * 16 + quad * 4) = o;
        }
      }
    }
  }

  // ===================== grid barrier (device-scope) =====================
  __syncthreads();
  if (tid == 0) {
    __threadfence();                       // release: ctx writes -> L2 wb
    atomicAdd(gctr, 1u);
    while (atomicAdd(gctr, 0u) < 256u) { } // device-scope atomic poll
  }
  __syncthreads();
  __threadfence();                         // acquire: invalidate stale lines

  // ===================== part 2: out = ctx @ WoT^T + bo =====================
  {
    constexpr int Kk = 1024, Nn = 1024;
    f16* As = (f16*)smem;                  // 2 x 128x64 f16 = 32KB
    f16* Bs = (f16*)(smem + 32768);        // 2 x 128x64 f16 = 32KB
    const int wm = w >> 2, wn = w & 3;     // 8 waves: 2 x 4
    const int gid = blockIdx.x;
    const int m0 = (gid >> 3) * 128, n0 = (gid & 7) * 128;

    f32x4 acc[4][2];
    for (int a = 0; a < 4; ++a)
      for (int b2 = 0; b2 < 2; ++b2)
        for (int r = 0; r < 4; ++r) acc[a][b2][r] = 0.f;

    auto stage2 = [&](int k0, int buf) {
      for (int p = 0; p < 2; ++p) {
        int slot = p * 512 + tid;
        int r = slot >> 3, gg = (slot & 7) ^ (r & 7);
        gload_lds16(ctx + (size_t)(m0 + r) * Kk + k0 + gg * 8,
                    (char*)As + buf * 16384 + (p * 512 + w * 64) * 16);
      }
      for (int p = 0; p < 2; ++p) {
        int slot = p * 512 + tid;
        int r = slot >> 3, gg = (slot & 7) ^ (r & 7);
        gload_lds16(WoT + (size_t)(n0 + r) * Kk + k0 + gg * 8,
                    (char*)Bs + buf * 16384 + (p * 512 + w * 64) * 16);
      }
    };

    stage2(0, 0);
    __syncthreads();
    for (int it = 0; it < Kk / 64; ++it) {
      const int cur = it & 1;
      if (it + 1 < Kk / 64) stage2((it + 1) * 64, cur ^ 1);
      for (int ks = 0; ks < 2; ++ks) {
        f16x8 af[4], bf[2];
        for (int t = 0; t < 4; ++t)
          af[t] = lds_frag(As + cur * 8192, wm * 64 + t * 16 + l16, ks * 4 + quad);
        for (int t = 0; t < 2; ++t)
          bf[t] = lds_frag(Bs + cur * 8192, wn * 32 + t * 16 + l16, ks * 4 + quad);
        for (int tm = 0; tm < 4; ++tm)
          for (int tn = 0; tn < 2; ++tn)
            acc[tm][tn] = MFMA32(af[tm], bf[tn], acc[tm][tn]);
      }
      __syncthreads();
    }

    for (int tm = 0; tm < 4; ++tm)
      for (int tn = 0; tn < 2; ++tn) {
        int n = n0 + wn * 32 + tn * 16 + l16;
        float bn = bo[n];
        for (int r = 0; r < 4; ++r) {
          int m = m0 + wm * 64 + tm * 16 + quad * 4 + r;
          out[(size_t)m * Nn + n] = acc[tm][tn][r] + bn;
        }
      }
  }
}

// ---------- launch ----------

extern "C" void kernel_launch(void* const* d_in, const int* in_sizes, int n_in,
                              void* d_out, int out_size, void* d_ws, size_t ws_size,
                              hipStream_t stream) {
  const float* x  = (const float*)d_in[0];
  const int* mask = (const int*)d_in[1];
  const float* Wq = (const float*)d_in[2];
  const float* bq = (const float*)d_in[3];
  const float* Wk = (const float*)d_in[4];
  const float* bk = (const float*)d_in[5];
  const float* Wv = (const float*)d_in[6];
  const float* bv = (const float*)d_in[7];
  const float* Wo = (const float*)d_in[8];
  const float* bo = (const float*)d_in[9];
  float* out = (float*)d_out;

  char* ws = (char*)d_ws;
  f16* xh      = (f16*)(ws);                            // 8 MB
  f16* Wqkv_t  = (f16*)(ws + (8u  << 20));              // 6 MB
  f16* Wot     = (f16*)(ws + (14u << 20));              // 2 MB
  float* bqkv  = (float*)(ws + (16u << 20));            // 12 KB
  float* maskf = (float*)(ws + (16u << 20) + 65536);    // 16 KB
  f16* QK      = (f16*)(ws + (17u << 20));              // 16 MB [4096][2048]
  f16* ctx     = (f16*)(ws + (34u << 20));              // 8 MB
  f16* VTr     = (f16*)(ws + (43u << 20));              // 8 MB [B][NH][64][T]
  unsigned* gctr = (unsigned*)(ws + (51u << 20));       // 4 B grid-barrier ctr

  hipMemsetAsync(gctr, 0, sizeof(unsigned), stream);

  pack_all<<<dim3(5164), 256, 0, stream>>>(x, Wq, Wk, Wv, Wo, bq, bk, bv, mask,
                                           xh, Wqkv_t, Wot, bqkv, maskf);

  gemm_qkv<<<dim3(3 * H / 64, M / 128), 256, 0, stream>>>(
      xh, Wqkv_t, bqkv, QK, VTr);

  attn_out<<<dim3(256), 512, 0, stream>>>(QK, VTr, maskf, ctx, Wot, bo, out,
                                          gctr);
}

// Round 9
// 185.421 us; speedup vs baseline: 1.2356x; 1.2356x over previous
//
#include <hip/hip_runtime.h>

typedef _Float16 f16;
typedef _Float16 f16x8 __attribute__((ext_vector_type(8)));
typedef _Float16 f16x4 __attribute__((ext_vector_type(4)));
typedef __fp16 h16x2 __attribute__((ext_vector_type(2)));
typedef float f32x4 __attribute__((ext_vector_type(4)));

#define MFMA32(a, b, c) __builtin_amdgcn_mfma_f32_16x16x32_f16((a), (b), (c), 0, 0, 0)

static constexpr int Bb = 2, T = 2048, H = 1024, NH = 16, HD = 64;
static constexpr int M = Bb * T;      // 4096 rows
static constexpr int NQK = 2 * H;     // QK buffer row stride (Q | K)
// fold 1/sqrt(64) * log2(e) into Wq/bq so P = 2^S via raw v_exp_f32
#define QSCALE 0.1803368801111f

__device__ __forceinline__ void gload_lds16(const void* g, void* l) {
  __builtin_amdgcn_global_load_lds(
      (const __attribute__((address_space(1))) void*)g,
      (__attribute__((address_space(3))) void*)l, 16, 0, 0);
}

// ---------- fused pack kernel v2: vectorized global access ----------
// x-convert: 8 floats/thread (2x float4 -> f16x8), 2048 blocks.
// W-transpose: float4 reads + f16x4 coalesced stores; LDS tile scalar [64][65].
// Grid: 2048 (x) + 1024 (W tiles) + 12 (bias) + 16 (mask) = 3100 blocks.
__global__ __launch_bounds__(256) void pack_all(const float* __restrict__ x,
                                                const float* __restrict__ Wq,
                                                const float* __restrict__ Wk,
                                                const float* __restrict__ Wv,
                                                const float* __restrict__ Wo,
                                                const float* __restrict__ bq,
                                                const float* __restrict__ bk,
                                                const float* __restrict__ bv,
                                                const int* __restrict__ mask,
                                                f16* __restrict__ xh,
                                                f16* __restrict__ WqkvT,
                                                f16* __restrict__ WoT,
                                                float* __restrict__ bqkv,
                                                float* __restrict__ maskf) {
  __shared__ f16 tile[64][65];
  const int bid = blockIdx.x;
  const int tid = threadIdx.x;
  if (bid < 2048) {
    // x -> f16, 8 elements/thread
    size_t i = ((size_t)bid * 256 + tid) * 8;
    float4 v0 = *(const float4*)(x + i);
    float4 v1 = *(const float4*)(x + i + 4);
    f16x8 o;
    o[0] = (f16)v0.x; o[1] = (f16)v0.y; o[2] = (f16)v0.z; o[3] = (f16)v0.w;
    o[4] = (f16)v1.x; o[5] = (f16)v1.y; o[6] = (f16)v1.z; o[7] = (f16)v1.w;
    *(f16x8*)(xh + i) = o;
  } else if (bid < 3072) {
    int t = bid - 2048;
    int z = t >> 8, rem = t & 255;
    const float* W = (z == 0) ? Wq : (z == 1) ? Wk : (z == 2) ? Wv : Wo;
    f16* Wt = (z < 3) ? (WqkvT + (size_t)z * H * H) : WoT;
    const float scale = (z == 0) ? QSCALE : 1.0f;
    int k0 = (rem >> 4) * 64, n0 = (rem & 15) * 64;
    // read: float4 loads, scalar LDS writes (4 per thread per pass)
    for (int p = 0; p < 4; ++p) {
      int j = tid + p * 256;              // 0..1023
      int r = j >> 4, c4 = (j & 15) * 4;
      float4 v = *(const float4*)&W[(size_t)(k0 + r) * H + n0 + c4];
      tile[r][c4 + 0] = (f16)(v.x * scale);
      tile[r][c4 + 1] = (f16)(v.y * scale);
      tile[r][c4 + 2] = (f16)(v.z * scale);
      tile[r][c4 + 3] = (f16)(v.w * scale);
    }
    __syncthreads();
    // write: scalar LDS reads (transpose), f16x4 coalesced global stores
    for (int p = 0; p < 4; ++p) {
      int j = tid + p * 256;
      int r = j >> 4, c4 = (j & 15) * 4;
      f16x4 o;
      o[0] = tile[c4 + 0][r];
      o[1] = tile[c4 + 1][r];
      o[2] = tile[c4 + 2][r];
      o[3] = tile[c4 + 3][r];
      *(f16x4*)&Wt[(size_t)(n0 + r) * H + k0 + c4] = o;
    }
  } else if (bid < 3084) {
    int i = (bid - 3072) * 256 + tid;
    if (i < 3072) {
      float v = (i < 1024) ? bq[i] * QSCALE : ((i < 2048) ? bk[i - 1024] : bv[i - 2048]);
      bqkv[i] = v;
    }
  } else {
    int i = (bid - 3084) * 256 + tid;
    // log2-domain mask bias: P = exp2(S + bias); 0 keeps, -3e4 kills (exp2 -> 0)
    if (i < Bb * T) maskf[i] = mask[i] ? 0.0f : -30000.0f;
  }
}

// LDS rows of 64 f16 = 8 granules; slot s of row r holds granule s^(r&7).
__device__ __forceinline__ f16x8 lds_frag(const f16* base, int row, int gr) {
  return *(const f16x8*)(base + row * 64 + ((gr ^ (row & 7)) << 3));
}

// ---------- GEMM1: [xh @ WqkvT^T + b] -> QK (n<2048) / VT transposed (n>=2048)
// r2-proven shape: TM=128, TN=64, (256,3) -> 3 blocks/CU. 8-phase 256^2
// rebuild regressed at K=1024 (r7); 128^2/(256,2) latency-bound (r5).
__global__ __launch_bounds__(256, 3) void gemm_qkv(const f16* __restrict__ A,
                                                   const f16* __restrict__ Bt,
                                                   const float* __restrict__ bias,
                                                   f16* __restrict__ QK,
                                                   f16* __restrict__ VT) {
  constexpr int TM = 128, TN = 64, Kk = 1024;
  __shared__ f16 As[2][TM * 64];
  __shared__ f16 Bs[2][TN * 64];
  const int tid = threadIdx.x;
  const int lane = tid & 63, w = tid >> 6;
  const int quad = lane >> 4, l16 = lane & 15;
  const int wm = w >> 1, wn = w & 1;
  const int m0 = blockIdx.y * TM, n0 = blockIdx.x * TN;

  f32x4 acc[4][2];
  for (int a = 0; a < 4; ++a)
    for (int b2 = 0; b2 < 2; ++b2)
      for (int r = 0; r < 4; ++r) acc[a][b2][r] = 0.f;

  auto stage = [&](int k0, int buf) {
    for (int p = 0; p < 4; ++p) {
      int slot = p * 256 + w * 64 + lane;
      int r = slot >> 3, g = (slot & 7) ^ (r & 7);
      gload_lds16(A + (size_t)(m0 + r) * Kk + k0 + g * 8,
                  (char*)&As[buf][0] + (p * 256 + w * 64) * 16);
    }
    for (int p = 0; p < 2; ++p) {
      int slot = p * 256 + w * 64 + lane;
      int r = slot >> 3, g = (slot & 7) ^ (r & 7);
      gload_lds16(Bt + (size_t)(n0 + r) * Kk + k0 + g * 8,
                  (char*)&Bs[buf][0] + (p * 256 + w * 64) * 16);
    }
  };

  stage(0, 0);
  __syncthreads();
  for (int it = 0; it < Kk / 64; ++it) {
    const int cur = it & 1;
    if (it + 1 < Kk / 64) stage((it + 1) * 64, cur ^ 1);
    for (int ks = 0; ks < 2; ++ks) {
      f16x8 af[4], bf[2];
      for (int t = 0; t < 4; ++t)
        af[t] = lds_frag(&As[cur][0], wm * 64 + t * 16 + l16, ks * 4 + quad);
      for (int t = 0; t < 2; ++t)
        bf[t] = lds_frag(&Bs[cur][0], wn * 32 + t * 16 + l16, ks * 4 + quad);
      for (int tm = 0; tm < 4; ++tm)
        for (int tn = 0; tn < 2; ++tn)
          acc[tm][tn] = MFMA32(af[tm], bf[tn], acc[tm][tn]);
    }
    __syncthreads();
  }

  if (n0 < 2048) {
    for (int tm = 0; tm < 4; ++tm)
      for (int tn = 0; tn < 2; ++tn) {
        int n = n0 + wn * 32 + tn * 16 + l16;
        float bn = bias[n];
        for (int r = 0; r < 4; ++r) {
          int m = m0 + wm * 64 + tm * 16 + quad * 4 + r;
          QK[(size_t)m * NQK + n] = (f16)(acc[tm][tn][r] + bn);
        }
      }
  } else {
    for (int tm = 0; tm < 4; ++tm)
      for (int tn = 0; tn < 2; ++tn) {
        int ng = n0 + wn * 32 + tn * 16 + l16;
        float bn = bias[ng];
        int n = ng - 2048;
        int h = n >> 6, d = n & 63;
        int mrow = m0 + wm * 64 + tm * 16 + quad * 4;
        int bb = mrow >> 11, t = mrow & 2047;
        int c = (t & ~127) | ((t + 8 * (d & 15)) & 127);
        f16x4 o;
        for (int r = 0; r < 4; ++r) o[r] = (f16)(acc[tm][tn][r] + bn);
        *(f16x4*)(VT + ((size_t)(bb * NH + h) * HD + d) * T + c) = o;
      }
  }
}

// ---------- GEMM2: out = ctx @ WoT^T + bo (f32 out) ----------
__global__ __launch_bounds__(256, 3) void gemm_out(const f16* __restrict__ A,
                                                   const f16* __restrict__ Bt,
                                                   const float* __restrict__ bias,
                                                   float* __restrict__ Cout) {
  constexpr int TM = 128, TN = 64, Kk = 1024, Nn = 1024;
  __shared__ f16 As[2][TM * 64];
  __shared__ f16 Bs[2][TN * 64];
  const int tid = threadIdx.x;
  const int lane = tid & 63, w = tid >> 6;
  const int quad = lane >> 4, l16 = lane & 15;
  const int wm = w >> 1, wn = w & 1;
  const int m0 = blockIdx.y * TM, n0 = blockIdx.x * TN;

  f32x4 acc[4][2];
  for (int a = 0; a < 4; ++a)
    for (int b2 = 0; b2 < 2; ++b2)
      for (int r = 0; r < 4; ++r) acc[a][b2][r] = 0.f;

  auto stage = [&](int k0, int buf) {
    for (int p = 0; p < 4; ++p) {
      int slot = p * 256 + w * 64 + lane;
      int r = slot >> 3, g = (slot & 7) ^ (r & 7);
      gload_lds16(A + (size_t)(m0 + r) * Kk + k0 + g * 8,
                  (char*)&As[buf][0] + (p * 256 + w * 64) * 16);
    }
    for (int p = 0; p < 2; ++p) {
      int slot = p * 256 + w * 64 + lane;
      int r = slot >> 3, g = (slot & 7) ^ (r & 7);
      gload_lds16(Bt + (size_t)(n0 + r) * Kk + k0 + g * 8,
                  (char*)&Bs[buf][0] + (p * 256 + w * 64) * 16);
    }
  };

  stage(0, 0);
  __syncthreads();
  for (int it = 0; it < Kk / 64; ++it) {
    const int cur = it & 1;
    if (it + 1 < Kk / 64) stage((it + 1) * 64, cur ^ 1);
    for (int ks = 0; ks < 2; ++ks) {
      f16x8 af[4], bf[2];
      for (int t = 0; t < 4; ++t)
        af[t] = lds_frag(&As[cur][0], wm * 64 + t * 16 + l16, ks * 4 + quad);
      for (int t = 0; t < 2; ++t)
        bf[t] = lds_frag(&Bs[cur][0], wn * 32 + t * 16 + l16, ks * 4 + quad);
      for (int tm = 0; tm < 4; ++tm)
        for (int tn = 0; tn < 2; ++tn)
          acc[tm][tn] = MFMA32(af[tm], bf[tn], acc[tm][tn]);
    }
    __syncthreads();
  }

  for (int tm = 0; tm < 4; ++tm)
    for (int tn = 0; tn < 2; ++tn) {
      int n = n0 + wn * 32 + tn * 16 + l16;
      float bn = bias[n];
      for (int r = 0; r < 4; ++r) {
        int m = m0 + wm * 64 + tm * 16 + quad * 4 + r;
        Cout[(size_t)m * Nn + n] = acc[tm][tn][r] + bn;
      }
    }
}

// ---------- flash attention v11 (r2-proven best; r5 remeasured 43.9us) ----------
// Block = 512 thr = 4 q-waves x 2 kv-groups; 256 q/block; kv tile 128 dbuf.
// Register-bound at 2 waves/SIMD; occupancy cannot rise (r1/r3/r4).
// Counted-vmcnt + setprio nulled (r6); grid-barrier fusion regressed (r8).
// Mask folded into QK MFMA C-in (log2 domain); row-sum via ones-vector MFMA.
// Bijective XCD swizzle: 256 blocks, 4 (b,h) per XCD -> 2MB KV per L2.

static constexpr int KT_ELE = 128 * 64;
static constexpr int VT_ELE = 64 * 128;

__global__ __launch_bounds__(512, 2) void attn_fused(const f16* __restrict__ QK,
                                                     const f16* __restrict__ VT,
                                                     const float* __restrict__ maskf,
                                                     f16* __restrict__ ctx) {
  __shared__ __align__(16) char smem[70656];  // staging 64KB | combine 70.6KB
  f16* KtB = (f16*)smem;
  f16* VtB = (f16*)(smem + 2 * KT_ELE * 2);

  const int tid = threadIdx.x;
  const int w = tid >> 6, lane = tid & 63;
  const int quad = lane >> 4, l16 = lane & 15;
  const int qw = w & 3, g = w >> 2;

  // XCD-aware bijective swizzle (256 blocks % 8 XCDs == 0):
  // each XCD gets 4 (b,h) pairs x 8 q-blocks -> K/V working set 2MB < 4MB L2
  const int flat = blockIdx.x + (T / 256) * (blockIdx.y + NH * blockIdx.z);
  const int xcd = flat & 7, idx = flat >> 3;   // idx 0..31 per XCD
  const int bh = xcd * 4 + (idx >> 3);         // 4 (b,h) pairs per XCD
  const int qb = idx & 7;                      // 8 q-blocks per (b,h)
  const int h = bh & 15, b = bh >> 4;
  const int q0 = qb * 256;

  const size_t kbase = (size_t)(b * T) * NQK + H + h * HD;
  const size_t vtbase = ((size_t)(b * NH + h) * HD) * T;
  const float* maskp = maskf + b * T;

  // Q B-frags
  f16x8 qf[4][2];
  for (int tq = 0; tq < 4; ++tq) {
    const f16* qrow = QK + (size_t)(b * T + q0 + qw * 64 + tq * 16 + l16) * NQK + h * HD;
    qf[tq][0] = *(const f16x8*)(qrow + quad * 8);
    qf[tq][1] = *(const f16x8*)(qrow + 32 + quad * 8);
  }

  f16x8 onesf;
  for (int i = 0; i < 8; ++i) onesf[i] = (f16)1.0f;

  f32x4 oacc[4][4];
  f32x4 lacc[4];
  for (int tq = 0; tq < 4; ++tq) {
    for (int r = 0; r < 4; ++r) lacc[tq][r] = 0.f;
    for (int t = 0; t < 4; ++t)
      for (int r = 0; r < 4; ++r) oacc[tq][t][r] = 0.f;
  }

  auto stage = [&](int kv0, int buf) {
    f16* Kd = KtB + buf * KT_ELE;
    f16* Vd = VtB + buf * VT_ELE;
    for (int p = 0; p < 2; ++p) {
      int s = p * 512 + tid;
      int R = s >> 3, sg = (s & 7) ^ (R & 7);
      int kv = (R & ~31) | ((R & 12) << 1) | ((R & 16) >> 2) | (R & 3);
      gload_lds16(QK + kbase + (size_t)(kv0 + kv) * NQK + sg * 8,
                  (char*)Kd + (p * 512 + w * 64) * 16);
    }
    for (int p = 0; p < 2; ++p) {
      int s = p * 512 + tid;
      int d = s >> 4, cg = s & 15;
      gload_lds16(VT + vtbase + (size_t)d * T + kv0 + cg * 8,
                  (char*)Vd + (p * 512 + w * 64) * 16);
    }
  };

  stage(0, 0);
  __syncthreads();

  for (int it = 0; it < T / 128; ++it) {
    const int cur = it & 1;
    if (it + 1 < T / 128) stage((it + 1) * 128, cur ^ 1);

    const f16* Kc = KtB + cur * KT_ELE;
    const f16* Vc = VtB + cur * VT_ELE;

    for (int s = 0; s < 2; ++s) {
      const int bi = g * 2 + s;               // 32-kv block index in tile
      const int kvabs = it * 128 + bi * 32;
      float4 m0 = *(const float4*)(maskp + kvabs + quad * 8);
      float4 m1 = *(const float4*)(maskp + kvabs + quad * 8 + 4);
      f32x4 zA, zB;
      zA[0] = m0.x; zA[1] = m0.y; zA[2] = m0.z; zA[3] = m0.w;
      zB[0] = m1.x; zB[1] = m1.y; zB[2] = m1.z; zB[3] = m1.w;
      f16x8 kfA0 = lds_frag(Kc, bi * 32 + l16, quad);
      f16x8 kfA1 = lds_frag(Kc, bi * 32 + l16, 4 + quad);
      f16x8 kfB0 = lds_frag(Kc, bi * 32 + 16 + l16, quad);
      f16x8 kfB1 = lds_frag(Kc, bi * 32 + 16 + l16, 4 + quad);
      f16x8 vf[4];
      for (int td = 0; td < 4; ++td)
        vf[td] = *(const f16x8*)&Vc[(td * 16 + l16) * 128 +
                                    ((bi * 32 + quad * 8 + 8 * l16) & 127)];

      // phase 1: all QK MFMAs (16, independent chains of 2); mask bias as C-in
      f32x4 sA[4], sB[4];
      for (int tq = 0; tq < 4; ++tq) {
        sA[tq] = MFMA32(kfA0, qf[tq][0], zA);
        sB[tq] = MFMA32(kfB0, qf[tq][0], zB);
      }
      for (int tq = 0; tq < 4; ++tq) {
        sA[tq] = MFMA32(kfA1, qf[tq][1], sA[tq]);
        sB[tq] = MFMA32(kfB1, qf[tq][1], sB[tq]);
      }

      // phase 2: softmax VALU (exp2 + pack only)
      f16x8 pf[4];
      for (int tq = 0; tq < 4; ++tq) {
        float pA0 = __builtin_amdgcn_exp2f(sA[tq][0]);
        float pA1 = __builtin_amdgcn_exp2f(sA[tq][1]);
        float pA2 = __builtin_amdgcn_exp2f(sA[tq][2]);
        float pA3 = __builtin_amdgcn_exp2f(sA[tq][3]);
        float pB0 = __builtin_amdgcn_exp2f(sB[tq][0]);
        float pB1 = __builtin_amdgcn_exp2f(sB[tq][1]);
        float pB2 = __builtin_amdgcn_exp2f(sB[tq][2]);
        float pB3 = __builtin_amdgcn_exp2f(sB[tq][3]);
        union PF { f16x8 v; h16x2 h[4]; } u;
        u.h[0] = __builtin_amdgcn_cvt_pkrtz(pA0, pA1);
        u.h[1] = __builtin_amdgcn_cvt_pkrtz(pA2, pA3);
        u.h[2] = __builtin_amdgcn_cvt_pkrtz(pB0, pB1);
        u.h[3] = __builtin_amdgcn_cvt_pkrtz(pB2, pB3);
        pf[tq] = u.v;
      }

      // phase 3: all PV MFMAs + ones-MFMA row-sum (20, independent accumulators)
      for (int tq = 0; tq < 4; ++tq) {
        for (int td = 0; td < 4; ++td)
          oacc[tq][td] = MFMA32(vf[td], pf[tq], oacc[tq][td]);
        lacc[tq] = MFMA32(onesf, pf[tq], lacc[tq]);
      }
    }
    __syncthreads();
  }

  // ---- combine the 2 kv-groups (additive partials; 68 floats, stride 69) ----
  float* cmb = (float*)smem;
  const int slot = qw * 64 + lane;
  if (g == 1) {
    float* dst = cmb + slot * 69;
    int i = 0;
    for (int tq = 0; tq < 4; ++tq)
      for (int td = 0; td < 4; ++td)
        for (int r = 0; r < 4; ++r) dst[i++] = oacc[tq][td][r];
    for (int tq = 0; tq < 4; ++tq) dst[64 + tq] = lacc[tq][0];
  }
  __syncthreads();
  if (g == 0) {
    const float* src = cmb + slot * 69;
    int i = 0;
    for (int tq = 0; tq < 4; ++tq)
      for (int td = 0; td < 4; ++td)
        for (int r = 0; r < 4; ++r) oacc[tq][td][r] += src[i++];

    for (int tq = 0; tq < 4; ++tq) {
      // lacc already holds the full k=32 reduce per column; no shuffles needed
      float l = lacc[tq][0] + src[64 + tq];
      float inv = 1.f / l;
      int row = b * T + q0 + qw * 64 + tq * 16 + l16;
      for (int td = 0; td < 4; ++td) {
        f16x4 o;
        for (int r = 0; r < 4; ++r) o[r] = (f16)(oacc[tq][td][r] * inv);
        *(f16x4*)(ctx + (size_t)row * H + h * HD + td * 16 + quad * 4) = o;
      }
    }
  }
}

// ---------- launch ----------

extern "C" void kernel_launch(void* const* d_in, const int* in_sizes, int n_in,
                              void* d_out, int out_size, void* d_ws, size_t ws_size,
                              hipStream_t stream) {
  const float* x  = (const float*)d_in[0];
  const int* mask = (const int*)d_in[1];
  const float* Wq = (const float*)d_in[2];
  const float* bq = (const float*)d_in[3];
  const float* Wk = (const float*)d_in[4];
  const float* bk = (const float*)d_in[5];
  const float* Wv = (const float*)d_in[6];
  const float* bv = (const float*)d_in[7];
  const float* Wo = (const float*)d_in[8];
  const float* bo = (const float*)d_in[9];
  float* out = (float*)d_out;

  char* ws = (char*)d_ws;
  f16* xh      = (f16*)(ws);                            // 8 MB
  f16* Wqkv_t  = (f16*)(ws + (8u  << 20));              // 6 MB
  f16* Wot     = (f16*)(ws + (14u << 20));              // 2 MB
  float* bqkv  = (float*)(ws + (16u << 20));            // 12 KB
  float* maskf = (float*)(ws + (16u << 20) + 65536);    // 16 KB
  f16* QK      = (f16*)(ws + (17u << 20));              // 16 MB [4096][2048]
  f16* ctx     = (f16*)(ws + (34u << 20));              // 8 MB
  f16* VTr     = (f16*)(ws + (43u << 20));              // 8 MB [B][NH][64][T]

  pack_all<<<dim3(3100), 256, 0, stream>>>(x, Wq, Wk, Wv, Wo, bq, bk, bv, mask,
                                           xh, Wqkv_t, Wot, bqkv, maskf);

  gemm_qkv<<<dim3(3 * H / 64, M / 128), 256, 0, stream>>>(
      xh, Wqkv_t, bqkv, QK, VTr);

  attn_fused<<<dim3(T / 256, NH, Bb), 512, 0, stream>>>(QK, VTr, maskf, ctx);

  gemm_out<<<dim3(H / 64, M / 128), 256, 0, stream>>>(ctx, Wot, bo, out);
}

// Round 10
// 184.940 us; speedup vs baseline: 1.2388x; 1.0026x over previous
//
#include <hip/hip_runtime.h>

typedef _Float16 f16;
typedef _Float16 f16x8 __attribute__((ext_vector_type(8)));
typedef _Float16 f16x4 __attribute__((ext_vector_type(4)));
typedef __fp16 h16x2 __attribute__((ext_vector_type(2)));
typedef float f32x4 __attribute__((ext_vector_type(4)));

#define MFMA32(a, b, c) __builtin_amdgcn_mfma_f32_16x16x32_f16((a), (b), (c), 0, 0, 0)

static constexpr int Bb = 2, T = 2048, H = 1024, NH = 16, HD = 64;
static constexpr int M = Bb * T;      // 4096 rows
static constexpr int NQK = 2 * H;     // QK buffer row stride (Q | K)
// fold 1/sqrt(64) * log2(e) into Wq/bq so P = 2^S via raw v_exp_f32
#define QSCALE 0.1803368801111f

__device__ __forceinline__ void gload_lds16(const void* g, void* l) {
  __builtin_amdgcn_global_load_lds(
      (const __attribute__((address_space(1))) void*)g,
      (__attribute__((address_space(3))) void*)l, 16, 0, 0);
}

// ---------- fused pack kernel v2: vectorized global access (r9, neutral-kept) --
__global__ __launch_bounds__(256) void pack_all(const float* __restrict__ x,
                                                const float* __restrict__ Wq,
                                                const float* __restrict__ Wk,
                                                const float* __restrict__ Wv,
                                                const float* __restrict__ Wo,
                                                const float* __restrict__ bq,
                                                const float* __restrict__ bk,
                                                const float* __restrict__ bv,
                                                const int* __restrict__ mask,
                                                f16* __restrict__ xh,
                                                f16* __restrict__ WqkvT,
                                                f16* __restrict__ WoT,
                                                float* __restrict__ bqkv,
                                                float* __restrict__ maskf) {
  __shared__ f16 tile[64][65];
  const int bid = blockIdx.x;
  const int tid = threadIdx.x;
  if (bid < 2048) {
    size_t i = ((size_t)bid * 256 + tid) * 8;
    float4 v0 = *(const float4*)(x + i);
    float4 v1 = *(const float4*)(x + i + 4);
    f16x8 o;
    o[0] = (f16)v0.x; o[1] = (f16)v0.y; o[2] = (f16)v0.z; o[3] = (f16)v0.w;
    o[4] = (f16)v1.x; o[5] = (f16)v1.y; o[6] = (f16)v1.z; o[7] = (f16)v1.w;
    *(f16x8*)(xh + i) = o;
  } else if (bid < 3072) {
    int t = bid - 2048;
    int z = t >> 8, rem = t & 255;
    const float* W = (z == 0) ? Wq : (z == 1) ? Wk : (z == 2) ? Wv : Wo;
    f16* Wt = (z < 3) ? (WqkvT + (size_t)z * H * H) : WoT;
    const float scale = (z == 0) ? QSCALE : 1.0f;
    int k0 = (rem >> 4) * 64, n0 = (rem & 15) * 64;
    for (int p = 0; p < 4; ++p) {
      int j = tid + p * 256;              // 0..1023
      int r = j >> 4, c4 = (j & 15) * 4;
      float4 v = *(const float4*)&W[(size_t)(k0 + r) * H + n0 + c4];
      tile[r][c4 + 0] = (f16)(v.x * scale);
      tile[r][c4 + 1] = (f16)(v.y * scale);
      tile[r][c4 + 2] = (f16)(v.z * scale);
      tile[r][c4 + 3] = (f16)(v.w * scale);
    }
    __syncthreads();
    for (int p = 0; p < 4; ++p) {
      int j = tid + p * 256;
      int r = j >> 4, c4 = (j & 15) * 4;
      f16x4 o;
      o[0] = tile[c4 + 0][r];
      o[1] = tile[c4 + 1][r];
      o[2] = tile[c4 + 2][r];
      o[3] = tile[c4 + 3][r];
      *(f16x4*)&Wt[(size_t)(n0 + r) * H + k0 + c4] = o;
    }
  } else if (bid < 3084) {
    int i = (bid - 3072) * 256 + tid;
    if (i < 3072) {
      float v = (i < 1024) ? bq[i] * QSCALE : ((i < 2048) ? bk[i - 1024] : bv[i - 2048]);
      bqkv[i] = v;
    }
  } else {
    int i = (bid - 3084) * 256 + tid;
    // log2-domain mask bias: P = exp2(S + bias); 0 keeps, -3e4 kills (exp2 -> 0)
    if (i < Bb * T) maskf[i] = mask[i] ? 0.0f : -30000.0f;
  }
}

// LDS rows of 64 f16 = 8 granules; slot s of row r holds granule s^(r&7).
__device__ __forceinline__ f16x8 lds_frag(const f16* base, int row, int gr) {
  return *(const f16x8*)(base + row * 64 + ((gr ^ (row & 7)) << 3));
}

// ---------- GEMM1: [xh @ WqkvT^T + b] -> QK (n<2048) / VT transposed (n>=2048)
// r2-proven shape: TM=128, TN=64, (256,3) -> 3 blocks/CU.
__global__ __launch_bounds__(256, 3) void gemm_qkv(const f16* __restrict__ A,
                                                   const f16* __restrict__ Bt,
                                                   const float* __restrict__ bias,
                                                   f16* __restrict__ QK,
                                                   f16* __restrict__ VT) {
  constexpr int TM = 128, TN = 64, Kk = 1024;
  __shared__ f16 As[2][TM * 64];
  __shared__ f16 Bs[2][TN * 64];
  const int tid = threadIdx.x;
  const int lane = tid & 63, w = tid >> 6;
  const int quad = lane >> 4, l16 = lane & 15;
  const int wm = w >> 1, wn = w & 1;
  const int m0 = blockIdx.y * TM, n0 = blockIdx.x * TN;

  f32x4 acc[4][2];
  for (int a = 0; a < 4; ++a)
    for (int b2 = 0; b2 < 2; ++b2)
      for (int r = 0; r < 4; ++r) acc[a][b2][r] = 0.f;

  auto stage = [&](int k0, int buf) {
    for (int p = 0; p < 4; ++p) {
      int slot = p * 256 + w * 64 + lane;
      int r = slot >> 3, g = (slot & 7) ^ (r & 7);
      gload_lds16(A + (size_t)(m0 + r) * Kk + k0 + g * 8,
                  (char*)&As[buf][0] + (p * 256 + w * 64) * 16);
    }
    for (int p = 0; p < 2; ++p) {
      int slot = p * 256 + w * 64 + lane;
      int r = slot >> 3, g = (slot & 7) ^ (r & 7);
      gload_lds16(Bt + (size_t)(n0 + r) * Kk + k0 + g * 8,
                  (char*)&Bs[buf][0] + (p * 256 + w * 64) * 16);
    }
  };

  stage(0, 0);
  __syncthreads();
  for (int it = 0; it < Kk / 64; ++it) {
    const int cur = it & 1;
    if (it + 1 < Kk / 64) stage((it + 1) * 64, cur ^ 1);
    for (int ks = 0; ks < 2; ++ks) {
      f16x8 af[4], bf[2];
      for (int t = 0; t < 4; ++t)
        af[t] = lds_frag(&As[cur][0], wm * 64 + t * 16 + l16, ks * 4 + quad);
      for (int t = 0; t < 2; ++t)
        bf[t] = lds_frag(&Bs[cur][0], wn * 32 + t * 16 + l16, ks * 4 + quad);
      for (int tm = 0; tm < 4; ++tm)
        for (int tn = 0; tn < 2; ++tn)
          acc[tm][tn] = MFMA32(af[tm], bf[tn], acc[tm][tn]);
    }
    __syncthreads();
  }

  if (n0 < 2048) {
    for (int tm = 0; tm < 4; ++tm)
      for (int tn = 0; tn < 2; ++tn) {
        int n = n0 + wn * 32 + tn * 16 + l16;
        float bn = bias[n];
        for (int r = 0; r < 4; ++r) {
          int m = m0 + wm * 64 + tm * 16 + quad * 4 + r;
          QK[(size_t)m * NQK + n] = (f16)(acc[tm][tn][r] + bn);
        }
      }
  } else {
    for (int tm = 0; tm < 4; ++tm)
      for (int tn = 0; tn < 2; ++tn) {
        int ng = n0 + wn * 32 + tn * 16 + l16;
        float bn = bias[ng];
        int n = ng - 2048;
        int h = n >> 6, d = n & 63;
        int mrow = m0 + wm * 64 + tm * 16 + quad * 4;
        int bb = mrow >> 11, t = mrow & 2047;
        int c = (t & ~127) | ((t + 8 * (d & 15)) & 127);
        f16x4 o;
        for (int r = 0; r < 4; ++r) o[r] = (f16)(acc[tm][tn][r] + bn);
        *(f16x4*)(VT + ((size_t)(bb * NH + h) * HD + d) * T + c) = o;
      }
  }
}

// ---------- GEMM2: out = ctx @ WoT^T + bo (f32 out) ----------
__global__ __launch_bounds__(256, 3) void gemm_out(const f16* __restrict__ A,
                                                   const f16* __restrict__ Bt,
                                                   const float* __restrict__ bias,
                                                   float* __restrict__ Cout) {
  constexpr int TM = 128, TN = 64, Kk = 1024, Nn = 1024;
  __shared__ f16 As[2][TM * 64];
  __shared__ f16 Bs[2][TN * 64];
  const int tid = threadIdx.x;
  const int lane = tid & 63, w = tid >> 6;
  const int quad = lane >> 4, l16 = lane & 15;
  const int wm = w >> 1, wn = w & 1;
  const int m0 = blockIdx.y * TM, n0 = blockIdx.x * TN;

  f32x4 acc[4][2];
  for (int a = 0; a < 4; ++a)
    for (int b2 = 0; b2 < 2; ++b2)
      for (int r = 0; r < 4; ++r) acc[a][b2][r] = 0.f;

  auto stage = [&](int k0, int buf) {
    for (int p = 0; p < 4; ++p) {
      int slot = p * 256 + w * 64 + lane;
      int r = slot >> 3, g = (slot & 7) ^ (r & 7);
      gload_lds16(A + (size_t)(m0 + r) * Kk + k0 + g * 8,
                  (char*)&As[buf][0] + (p * 256 + w * 64) * 16);
    }
    for (int p = 0; p < 2; ++p) {
      int slot = p * 256 + w * 64 + lane;
      int r = slot >> 3, g = (slot & 7) ^ (r & 7);
      gload_lds16(Bt + (size_t)(n0 + r) * Kk + k0 + g * 8,
                  (char*)&Bs[buf][0] + (p * 256 + w * 64) * 16);
    }
  };

  stage(0, 0);
  __syncthreads();
  for (int it = 0; it < Kk / 64; ++it) {
    const int cur = it & 1;
    if (it + 1 < Kk / 64) stage((it + 1) * 64, cur ^ 1);
    for (int ks = 0; ks < 2; ++ks) {
      f16x8 af[4], bf[2];
      for (int t = 0; t < 4; ++t)
        af[t] = lds_frag(&As[cur][0], wm * 64 + t * 16 + l16, ks * 4 + quad);
      for (int t = 0; t < 2; ++t)
        bf[t] = lds_frag(&Bs[cur][0], wn * 32 + t * 16 + l16, ks * 4 + quad);
      for (int tm = 0; tm < 4; ++tm)
        for (int tn = 0; tn < 2; ++tn)
          acc[tm][tn] = MFMA32(af[tm], bf[tn], acc[tm][tn]);
    }
    __syncthreads();
  }

  for (int tm = 0; tm < 4; ++tm)
    for (int tn = 0; tn < 2; ++tn) {
      int n = n0 + wn * 32 + tn * 16 + l16;
      float bn = bias[n];
      for (int r = 0; r < 4; ++r) {
        int m = m0 + wm * 64 + tm * 16 + quad * 4 + r;
        Cout[(size_t)m * Nn + n] = acc[tm][tn][r] + bn;
      }
    }
}

// ---------- flash attention v16: v11 + s0/s1 interleave (T15 mechanism) ------
// Block = 512 thr = 4 q-waves x 2 kv-groups; 256 q/block; kv tile 128 dbuf.
// The two 32-kv sub-blocks are software-pipelined WITHIN the wave:
//   QK(s0) -> [s1 frag ds_reads] -> QK(s1) -> SM(s0) -> PV(s0) || SM(s1) -> PV(s1)
// Every VALU phase sits adjacent to an independent MFMA cluster, filling the
// ~40% both-pipes-idle gap the counters show at barrier-lockstep (r9:
// MfmaUtil 30 + VALUBusy 28). Register cost: 2nd s/kf/vf set, ~+70 VGPR,
// still <=256 so 2 waves/SIMD unchanged. All other techniques as r2/r9.

static constexpr int KT_ELE = 128 * 64;
static constexpr int VT_ELE = 64 * 128;

__global__ __launch_bounds__(512, 2) void attn_fused(const f16* __restrict__ QK,
                                                     const f16* __restrict__ VT,
                                                     const float* __restrict__ maskf,
                                                     f16* __restrict__ ctx) {
  __shared__ __align__(16) char smem[70656];  // staging 64KB | combine 70.6KB
  f16* KtB = (f16*)smem;
  f16* VtB = (f16*)(smem + 2 * KT_ELE * 2);

  const int tid = threadIdx.x;
  const int w = tid >> 6, lane = tid & 63;
  const int quad = lane >> 4, l16 = lane & 15;
  const int qw = w & 3, g = w >> 2;

  // XCD-aware bijective swizzle (256 blocks % 8 XCDs == 0)
  const int flat = blockIdx.x + (T / 256) * (blockIdx.y + NH * blockIdx.z);
  const int xcd = flat & 7, idx = flat >> 3;   // idx 0..31 per XCD
  const int bh = xcd * 4 + (idx >> 3);         // 4 (b,h) pairs per XCD
  const int qb = idx & 7;                      // 8 q-blocks per (b,h)
  const int h = bh & 15, b = bh >> 4;
  const int q0 = qb * 256;

  const size_t kbase = (size_t)(b * T) * NQK + H + h * HD;
  const size_t vtbase = ((size_t)(b * NH + h) * HD) * T;
  const float* maskp = maskf + b * T;

  // Q B-frags
  f16x8 qf[4][2];
  for (int tq = 0; tq < 4; ++tq) {
    const f16* qrow = QK + (size_t)(b * T + q0 + qw * 64 + tq * 16 + l16) * NQK + h * HD;
    qf[tq][0] = *(const f16x8*)(qrow + quad * 8);
    qf[tq][1] = *(const f16x8*)(qrow + 32 + quad * 8);
  }

  f16x8 onesf;
  for (int i = 0; i < 8; ++i) onesf[i] = (f16)1.0f;

  f32x4 oacc[4][4];
  f32x4 lacc[4];
  for (int tq = 0; tq < 4; ++tq) {
    for (int r = 0; r < 4; ++r) lacc[tq][r] = 0.f;
    for (int t = 0; t < 4; ++t)
      for (int r = 0; r < 4; ++r) oacc[tq][t][r] = 0.f;
  }

  auto stage = [&](int kv0, int buf) {
    f16* Kd = KtB + buf * KT_ELE;
    f16* Vd = VtB + buf * VT_ELE;
    for (int p = 0; p < 2; ++p) {
      int s = p * 512 + tid;
      int R = s >> 3, sg = (s & 7) ^ (R & 7);
      int kv = (R & ~31) | ((R & 12) << 1) | ((R & 16) >> 2) | (R & 3);
      gload_lds16(QK + kbase + (size_t)(kv0 + kv) * NQK + sg * 8,
                  (char*)Kd + (p * 512 + w * 64) * 16);
    }
    for (int p = 0; p < 2; ++p) {
      int s = p * 512 + tid;
      int d = s >> 4, cg = s & 15;
      gload_lds16(VT + vtbase + (size_t)d * T + kv0 + cg * 8,
                  (char*)Vd + (p * 512 + w * 64) * 16);
    }
  };

  stage(0, 0);
  __syncthreads();

  for (int it = 0; it < T / 128; ++it) {
    const int cur = it & 1;
    if (it + 1 < T / 128) stage((it + 1) * 128, cur ^ 1);

    const f16* Kc = KtB + cur * KT_ELE;
    const f16* Vc = VtB + cur * VT_ELE;

    const int bi0 = g * 2, bi1 = g * 2 + 1;
    const int kv0abs = it * 128 + bi0 * 32;
    const int kv1abs = it * 128 + bi1 * 32;

    float4 ma0 = *(const float4*)(maskp + kv0abs + quad * 8);
    float4 ma1 = *(const float4*)(maskp + kv0abs + quad * 8 + 4);
    float4 mb0 = *(const float4*)(maskp + kv1abs + quad * 8);
    float4 mb1 = *(const float4*)(maskp + kv1abs + quad * 8 + 4);
    f32x4 zA0, zB0, zA1, zB1;
    zA0[0] = ma0.x; zA0[1] = ma0.y; zA0[2] = ma0.z; zA0[3] = ma0.w;
    zB0[0] = ma1.x; zB0[1] = ma1.y; zB0[2] = ma1.z; zB0[3] = ma1.w;
    zA1[0] = mb0.x; zA1[1] = mb0.y; zA1[2] = mb0.z; zA1[3] = mb0.w;
    zB1[0] = mb1.x; zB1[1] = mb1.y; zB1[2] = mb1.z; zB1[3] = mb1.w;

    // ---- s0 K frags + QK(s0) ----
    f16x8 kA0_0 = lds_frag(Kc, bi0 * 32 + l16, quad);
    f16x8 kA1_0 = lds_frag(Kc, bi0 * 32 + l16, 4 + quad);
    f16x8 kB0_0 = lds_frag(Kc, bi0 * 32 + 16 + l16, quad);
    f16x8 kB1_0 = lds_frag(Kc, bi0 * 32 + 16 + l16, 4 + quad);

    f32x4 sA0[4], sB0[4];
    for (int tq = 0; tq < 4; ++tq) {
      sA0[tq] = MFMA32(kA0_0, qf[tq][0], zA0);
      sB0[tq] = MFMA32(kB0_0, qf[tq][0], zB0);
    }
    for (int tq = 0; tq < 4; ++tq) {
      sA0[tq] = MFMA32(kA1_0, qf[tq][1], sA0[tq]);
      sB0[tq] = MFMA32(kB1_0, qf[tq][1], sB0[tq]);
    }

    // ---- s1 K frags + both V frags (ds_reads hide under QK(s0) latency) ----
    f16x8 kA0_1 = lds_frag(Kc, bi1 * 32 + l16, quad);
    f16x8 kA1_1 = lds_frag(Kc, bi1 * 32 + l16, 4 + quad);
    f16x8 kB0_1 = lds_frag(Kc, bi1 * 32 + 16 + l16, quad);
    f16x8 kB1_1 = lds_frag(Kc, bi1 * 32 + 16 + l16, 4 + quad);
    f16x8 vf0[4], vf1[4];
    for (int td = 0; td < 4; ++td)
      vf0[td] = *(const f16x8*)&Vc[(td * 16 + l16) * 128 +
                                   ((bi0 * 32 + quad * 8 + 8 * l16) & 127)];
    for (int td = 0; td < 4; ++td)
      vf1[td] = *(const f16x8*)&Vc[(td * 16 + l16) * 128 +
                                   ((bi1 * 32 + quad * 8 + 8 * l16) & 127)];

    // ---- QK(s1) ----
    f32x4 sA1[4], sB1[4];
    for (int tq = 0; tq < 4; ++tq) {
      sA1[tq] = MFMA32(kA0_1, qf[tq][0], zA1);
      sB1[tq] = MFMA32(kB0_1, qf[tq][0], zB1);
    }
    for (int tq = 0; tq < 4; ++tq) {
      sA1[tq] = MFMA32(kA1_1, qf[tq][1], sA1[tq]);
      sB1[tq] = MFMA32(kB1_1, qf[tq][1], sB1[tq]);
    }

    // ---- SM(s0) -> pf0 ----
    f16x8 pf0[4];
    for (int tq = 0; tq < 4; ++tq) {
      float pA0 = __builtin_amdgcn_exp2f(sA0[tq][0]);
      float pA1 = __builtin_amdgcn_exp2f(sA0[tq][1]);
      float pA2 = __builtin_amdgcn_exp2f(sA0[tq][2]);
      float pA3 = __builtin_amdgcn_exp2f(sA0[tq][3]);
      float pB0 = __builtin_amdgcn_exp2f(sB0[tq][0]);
      float pB1 = __builtin_amdgcn_exp2f(sB0[tq][1]);
      float pB2 = __builtin_amdgcn_exp2f(sB0[tq][2]);
      float pB3 = __builtin_amdgcn_exp2f(sB0[tq][3]);
      union PF { f16x8 v; h16x2 h[4]; } u;
      u.h[0] = __builtin_amdgcn_cvt_pkrtz(pA0, pA1);
      u.h[1] = __builtin_amdgcn_cvt_pkrtz(pA2, pA3);
      u.h[2] = __builtin_amdgcn_cvt_pkrtz(pB0, pB1);
      u.h[3] = __builtin_amdgcn_cvt_pkrtz(pB2, pB3);
      pf0[tq] = u.v;
    }

    // ---- PV(s0) (MFMA) -- independent of SM(s1): scheduler may interleave --
    for (int tq = 0; tq < 4; ++tq) {
      for (int td = 0; td < 4; ++td)
        oacc[tq][td] = MFMA32(vf0[td], pf0[tq], oacc[tq][td]);
      lacc[tq] = MFMA32(onesf, pf0[tq], lacc[tq]);
    }

    // ---- SM(s1) -> pf1 ----
    f16x8 pf1[4];
    for (int tq = 0; tq < 4; ++tq) {
      float pA0 = __builtin_amdgcn_exp2f(sA1[tq][0]);
      float pA1 = __builtin_amdgcn_exp2f(sA1[tq][1]);
      float pA2 = __builtin_amdgcn_exp2f(sA1[tq][2]);
      float pA3 = __builtin_amdgcn_exp2f(sA1[tq][3]);
      float pB0 = __builtin_amdgcn_exp2f(sB1[tq][0]);
      float pB1 = __builtin_amdgcn_exp2f(sB1[tq][1]);
      float pB2 = __builtin_amdgcn_exp2f(sB1[tq][2]);
      float pB3 = __builtin_amdgcn_exp2f(sB1[tq][3]);
      union PF { f16x8 v; h16x2 h[4]; } u;
      u.h[0] = __builtin_amdgcn_cvt_pkrtz(pA0, pA1);
      u.h[1] = __builtin_amdgcn_cvt_pkrtz(pA2, pA3);
      u.h[2] = __builtin_amdgcn_cvt_pkrtz(pB0, pB1);
      u.h[3] = __builtin_amdgcn_cvt_pkrtz(pB2, pB3);
      pf1[tq] = u.v;
    }

    // ---- PV(s1) ----
    for (int tq = 0; tq < 4; ++tq) {
      for (int td = 0; td < 4; ++td)
        oacc[tq][td] = MFMA32(vf1[td], pf1[tq], oacc[tq][td]);
      lacc[tq] = MFMA32(onesf, pf1[tq], lacc[tq]);
    }

    __syncthreads();
  }

  // ---- combine the 2 kv-groups (additive partials; 68 floats, stride 69) ----
  float* cmb = (float*)smem;
  const int slot = qw * 64 + lane;
  if (g == 1) {
    float* dst = cmb + slot * 69;
    int i = 0;
    for (int tq = 0; tq < 4; ++tq)
      for (int td = 0; td < 4; ++td)
        for (int r = 0; r < 4; ++r) dst[i++] = oacc[tq][td][r];
    for (int tq = 0; tq < 4; ++tq) dst[64 + tq] = lacc[tq][0];
  }
  __syncthreads();
  if (g == 0) {
    const float* src = cmb + slot * 69;
    int i = 0;
    for (int tq = 0; tq < 4; ++tq)
      for (int td = 0; td < 4; ++td)
        for (int r = 0; r < 4; ++r) oacc[tq][td][r] += src[i++];

    for (int tq = 0; tq < 4; ++tq) {
      // lacc already holds the full k=32 reduce per column; no shuffles needed
      float l = lacc[tq][0] + src[64 + tq];
      float inv = 1.f / l;
      int row = b * T + q0 + qw * 64 + tq * 16 + l16;
      for (int td = 0; td < 4; ++td) {
        f16x4 o;
        for (int r = 0; r < 4; ++r) o[r] = (f16)(oacc[tq][td][r] * inv);
        *(f16x4*)(ctx + (size_t)row * H + h * HD + td * 16 + quad * 4) = o;
      }
    }
  }
}

// ---------- launch ----------

extern "C" void kernel_launch(void* const* d_in, const int* in_sizes, int n_in,
                              void* d_out, int out_size, void* d_ws, size_t ws_size,
                              hipStream_t stream) {
  const float* x  = (const float*)d_in[0];
  const int* mask = (const int*)d_in[1];
  const float* Wq = (const float*)d_in[2];
  const float* bq = (const float*)d_in[3];
  const float* Wk = (const float*)d_in[4];
  const float* bk = (const float*)d_in[5];
  const float* Wv = (const float*)d_in[6];
  const float* bv = (const float*)d_in[7];
  const float* Wo = (const float*)d_in[8];
  const float* bo = (const float*)d_in[9];
  float* out = (float*)d_out;

  char* ws = (char*)d_ws;
  f16* xh      = (f16*)(ws);                            // 8 MB
  f16* Wqkv_t  = (f16*)(ws + (8u  << 20));              // 6 MB
  f16* Wot     = (f16*)(ws + (14u << 20));              // 2 MB
  float* bqkv  = (float*)(ws + (16u << 20));            // 12 KB
  float* maskf = (float*)(ws + (16u << 20) + 65536);    // 16 KB
  f16* QK      = (f16*)(ws + (17u << 20));              // 16 MB [4096][2048]
  f16* ctx     = (f16*)(ws + (34u << 20));              // 8 MB
  f16* VTr     = (f16*)(ws + (43u << 20));              // 8 MB [B][NH][64][T]

  pack_all<<<dim3(3100), 256, 0, stream>>>(x, Wq, Wk, Wv, Wo, bq, bk, bv, mask,
                                           xh, Wqkv_t, Wot, bqkv, maskf);

  gemm_qkv<<<dim3(3 * H / 64, M / 128), 256, 0, stream>>>(
      xh, Wqkv_t, bqkv, QK, VTr);

  attn_fused<<<dim3(T / 256, NH, Bb), 512, 0, stream>>>(QK, VTr, maskf, ctx);

  gemm_out<<<dim3(H / 64, M / 128), 256, 0, stream>>>(ctx, Wot, bo, out);
}